// Round 1
// baseline (175.829 us; speedup 1.0000x reference)
//
#include <hip/hip_runtime.h>

#define IN_DIM  4096
#define OUT_DIM 4096
#define RANK    16
#define NBLK    16          // 16 blocks along each of in/out
#define KDIM    256         // NBLK * RANK

// ---------------------------------------------------------------------------
// ws layout (floats):
//   Ahat    : [KDIM][OUT_DIM]          = 4 MB      offset 0
//   Tt      : [KDIM][M]                = 2 MB      offset 4 MB
//   rowsum_p: [NBLK][M]  (per-i partials) = 128 KB  offset 6 MB
// ---------------------------------------------------------------------------

// Ahat[(i,r)][(o,q)] = S[o,i,r] * U[o,r,q]
__global__ __launch_bounds__(256) void build_ahat(const float* __restrict__ S,
                                                  const float* __restrict__ U,
                                                  float4* __restrict__ Ahat4) {
    int t  = blockIdx.x * 256 + threadIdx.x;  // float4 id, 0..262143
    int k  = t >> 10;                         // 0..255   (= i*16 + r)
    int n4 = t & 1023;                        // float4 col id
    int i = k >> 4, r = k & 15;
    int o = n4 >> 6, q4 = n4 & 63;
    float  s = S[(o * NBLK + i) * RANK + r];
    float4 u = reinterpret_cast<const float4*>(U)[(o * RANK + r) * 64 + q4];
    float4 w;
    w.x = s * u.x; w.y = s * u.y; w.z = s * u.z; w.w = s * u.w;
    Ahat4[t] = w;
}

// Tt[(i*16+r)][m] = sum_p x[m][i*256+p] * Vt[i][p][r];  rowsum_p[i][m] = sum_p x[m][i*256+p]
// grid (M/64, NBLK), block = 1 wave (64 threads), lane = row within 64-row tile
__global__ __launch_bounds__(64) void factor_x(const float* __restrict__ x,
                                               const float* __restrict__ Vt,
                                               float* __restrict__ Tt,
                                               float* __restrict__ rowsum_p,
                                               int M) {
    __shared__ float xs[64][33];              // stride 33 -> read bank = (lane+p)%32, 2-way (free)
    const int lane = threadIdx.x;             // 0..63 = row
    const int i    = blockIdx.y;
    const int m0   = blockIdx.x * 64;
    const float* __restrict__ vt = Vt + (size_t)i * 256 * RANK;  // [256][16], wave-uniform -> s_load

    float acc[RANK];
#pragma unroll
    for (int r = 0; r < RANK; ++r) acc[r] = 0.0f;
    float rs = 0.0f;

    for (int pc = 0; pc < 8; ++pc) {          // 8 chunks of 32 p
        // stage 64 rows x 32 p, coalesced float4 global loads
#pragma unroll
        for (int e = 0; e < 8; ++e) {
            int ff  = e * 64 + lane;          // float4 id in chunk (512 total)
            int row = ff >> 3;                // 8 float4 per row
            int p4  = ff & 7;
            float4 v = *reinterpret_cast<const float4*>(
                x + (size_t)(m0 + row) * IN_DIM + i * 256 + pc * 32 + p4 * 4);
            // scalar LDS writes (stride-33 rows are not 16B aligned); ~2-way conflicts
            xs[row][p4 * 4 + 0] = v.x;
            xs[row][p4 * 4 + 1] = v.y;
            xs[row][p4 * 4 + 2] = v.z;
            xs[row][p4 * 4 + 3] = v.w;
        }
        __syncthreads();
#pragma unroll 8
        for (int p = 0; p < 32; ++p) {
            float xv = xs[lane][p];
            rs += xv;
            int pp = pc * 32 + p;
#pragma unroll
            for (int r = 0; r < RANK; ++r)
                acc[r] = fmaf(xv, vt[pp * RANK + r], acc[r]);  // s_load operand on SMEM pipe
        }
        __syncthreads();
    }
#pragma unroll
    for (int r = 0; r < RANK; ++r)
        Tt[(size_t)(i * RANK + r) * M + m0 + lane] = acc[r];   // transposed store, coalesced
    rowsum_p[(size_t)i * M + m0 + lane] = rs;                  // per-i partial, no atomics
}

// out[m][n] = sum_k Tt[k][m]*Ahat[k][n] + (1 + sum_i rowsum_p[i][m]) * bias[n]
// grid (OUT_DIM/1024, M/16), 256 threads; thread owns one float4 column group
__global__ __launch_bounds__(256) void apply_out(const float4* __restrict__ Ahat4,
                                                 const float* __restrict__ Tt,
                                                 const float* __restrict__ rowsum_p,
                                                 const float4* __restrict__ bias4,
                                                 float4* __restrict__ out4,
                                                 int M) {
    const int n4 = blockIdx.x * 256 + threadIdx.x;  // 0..1023
    const int m0 = blockIdx.y * 16;

    float4 acc[16];
#pragma unroll
    for (int mm = 0; mm < 16; ++mm) acc[mm] = make_float4(0.f, 0.f, 0.f, 0.f);

#pragma unroll 2
    for (int k = 0; k < KDIM; ++k) {
        float4 a = Ahat4[(size_t)k * (OUT_DIM / 4) + n4];      // coalesced, L2-resident
#pragma unroll
        for (int mm = 0; mm < 16; ++mm) {
            float tv = Tt[(size_t)k * M + m0 + mm];            // uniform -> s_load_dwordx
            acc[mm].x = fmaf(tv, a.x, acc[mm].x);
            acc[mm].y = fmaf(tv, a.y, acc[mm].y);
            acc[mm].z = fmaf(tv, a.z, acc[mm].z);
            acc[mm].w = fmaf(tv, a.w, acc[mm].w);
        }
    }

    float4 b = bias4[n4];
#pragma unroll
    for (int mm = 0; mm < 16; ++mm) {
        float sc = 1.0f;                                       // the "+bias" term
#pragma unroll
        for (int i = 0; i < NBLK; ++i) sc += rowsum_p[(size_t)i * M + m0 + mm];
        float4 o;
        o.x = fmaf(sc, b.x, acc[mm].x);
        o.y = fmaf(sc, b.y, acc[mm].y);
        o.z = fmaf(sc, b.z, acc[mm].z);
        o.w = fmaf(sc, b.w, acc[mm].w);
        out4[(size_t)(m0 + mm) * (OUT_DIM / 4) + n4] = o;
    }
}

extern "C" void kernel_launch(void* const* d_in, const int* in_sizes, int n_in,
                              void* d_out, int out_size, void* d_ws, size_t ws_size,
                              hipStream_t stream) {
    const float* x    = (const float*)d_in[0];
    const float* S    = (const float*)d_in[1];
    const float* U    = (const float*)d_in[2];
    const float* Vt   = (const float*)d_in[3];
    const float* bias = (const float*)d_in[4];
    float* out = (float*)d_out;
    const int M = in_sizes[0] / IN_DIM;   // 2048

    char* ws = (char*)d_ws;
    float* Ahat     = (float*)ws;                                           // 4 MB
    float* Tt       = (float*)(ws + (size_t)KDIM * OUT_DIM * 4);            // 2 MB
    float* rowsum_p = (float*)(ws + (size_t)KDIM * OUT_DIM * 4
                                  + (size_t)KDIM * M * 4);                  // 128 KB

    build_ahat<<<KDIM * OUT_DIM / 4 / 256, 256, 0, stream>>>(S, U, (float4*)Ahat);
    factor_x<<<dim3(M / 64, NBLK), 64, 0, stream>>>(x, Vt, Tt, rowsum_p, M);
    apply_out<<<dim3(OUT_DIM / 1024, M / 16), 256, 0, stream>>>(
        (const float4*)Ahat, Tt, rowsum_p, (const float4*)bias, (float4*)out, M);
}

// Round 3
// 115.944 us; speedup vs baseline: 1.5165x; 1.5165x over previous
//
#include <hip/hip_runtime.h>

#define IN_DIM  4096
#define OUT_DIM 4096
#define RANK    16
#define NBLK    16
#define KDIM    256   // NBLK*RANK

typedef __attribute__((ext_vector_type(8))) __bf16 bf16x8;
typedef __attribute__((ext_vector_type(4))) float  f32x4;
typedef __attribute__((ext_vector_type(4))) unsigned short u16x4;
typedef __attribute__((ext_vector_type(8))) unsigned short u16x8;

__device__ __forceinline__ unsigned short bf16_rne(float v) {
    unsigned u = __float_as_uint(v);
    unsigned r = (u + 0x7FFFu + ((u >> 16) & 1u)) >> 16;
    return (unsigned short)r;
}
__device__ __forceinline__ float bf16_f32(unsigned short h) {
    return __uint_as_float(((unsigned)h) << 16);
}

// ---------------------------------------------------------------------------
// Pack layouts (MFMA 16x16x32 fragment order), elem granularity = u16x8 (16B):
//   PackA[mt(128)][ko(32)][c(16)] : 8 bf16 = T[mt*16+c][ko*8 + j]   (A row=c)
//   PackB[nt(256)][ko(32)][c(16)] : 8 bf16 = Ahat[ko*8+j][nt*16+c]  (B col=c)
// Lane l of a wave loads index ((t*32 + 4s + (l>>4))*16 + (l&15)) -> per-wave
// contiguous 1KB, per-lane 16B.
// ---------------------------------------------------------------------------

// Ahat[(i,r)][(o,q)] = S[o,i,r] * U[o,r,q], split into bf16 hi+lo, packed.
__global__ __launch_bounds__(256) void build_packB(const float* __restrict__ S,
                                                   const float* __restrict__ U,
                                                   u16x8* __restrict__ Bhi,
                                                   u16x8* __restrict__ Blo) {
    int t  = blockIdx.x * 256 + threadIdx.x;  // = (nt*32 + ko)*16 + c
    int c  = t & 15;
    int ko = (t >> 4) & 31;
    int nt = t >> 9;
    int o  = nt >> 4;
    int i  = ko >> 1;
    int q  = ((nt & 15) << 4) | c;
    int r0 = (ko & 1) << 3;
    const float* Sp = S + ((o * NBLK + i) * RANK + r0);
    const float* Up = U + (size_t)o * RANK * 256 + q;   // + r*256
    u16x8 hi, lo;
#pragma unroll
    for (int j = 0; j < 8; ++j) {
        float w = Sp[j] * Up[(size_t)(r0 + j) * 256];
        unsigned short h = bf16_rne(w);
        hi[j] = h;
        lo[j] = bf16_rne(w - bf16_f32(h));
    }
    Bhi[t] = hi;
    Blo[t] = lo;
}

// T[m][(i,r)] = sum_p x[m][i*256+p]*Vt[i][p][r]; also rowsum partials.
// grid (M/64, NBLK), 256 thr = 4 waves; wave w owns p-slice, all 16 r.
__global__ __launch_bounds__(256) void factor_x(const float* __restrict__ x,
                                                const float* __restrict__ Vt,
                                                u16x4* __restrict__ Ahi4,
                                                u16x4* __restrict__ Alo4,
                                                float* __restrict__ rowsum_p,
                                                int M) {
    __shared__ float xs[64][129];     // odd stride: read bank (lane+p)%32, 2-way = free
    __shared__ float ps[4][64][17];
    const int tid  = threadIdx.x;
    const int lane = tid & 63;
    const int w    = __builtin_amdgcn_readfirstlane(tid >> 6);
    const int i    = blockIdx.y;
    const int m0   = blockIdx.x * 64;
    const float* __restrict__ vt = Vt + (size_t)i * 256 * RANK;

    float acc[16];
#pragma unroll
    for (int r = 0; r < RANK; ++r) acc[r] = 0.0f;
    float rs = 0.0f;

#pragma unroll
    for (int ch = 0; ch < 2; ++ch) {
        // stage 64 rows x 128 p, coalesced float4 loads
#pragma unroll
        for (int e = 0; e < 8; ++e) {
            int f   = e * 256 + tid;       // 2048 float4
            int row = f >> 5;
            int c4  = f & 31;
            float4 v = *reinterpret_cast<const float4*>(
                x + (size_t)(m0 + row) * IN_DIM + i * 256 + ch * 128 + c4 * 4);
            xs[row][c4 * 4 + 0] = v.x;
            xs[row][c4 * 4 + 1] = v.y;
            xs[row][c4 * 4 + 2] = v.z;
            xs[row][c4 * 4 + 3] = v.w;
        }
        __syncthreads();
        const int p0 = w * 32;
#pragma unroll 8
        for (int p = 0; p < 32; ++p) {
            float xv = xs[lane][p0 + p];
            rs += xv;
            const float* vp = vt + (size_t)(ch * 128 + p0 + p) * RANK;  // wave-uniform -> s_load
#pragma unroll
            for (int r = 0; r < RANK; ++r) acc[r] = fmaf(xv, vp[r], acc[r]);
        }
        __syncthreads();
    }

#pragma unroll
    for (int r = 0; r < RANK; ++r) ps[w][lane][r] = acc[r];
    ps[w][lane][16] = rs;
    __syncthreads();

    // reduce across waves; thread (m = lane, rg = w) handles r = 4*rg..4*rg+3
    const int m  = lane;
    const int rg = w;
    float v4[4];
#pragma unroll
    for (int rr = 0; rr < 4; ++rr) {
        int r = rg * 4 + rr;
        v4[rr] = ps[0][m][r] + ps[1][m][r] + ps[2][m][r] + ps[3][m][r];
    }
    const int gm = m0 + m;
    const int mt = gm >> 4, cc = gm & 15;
    const int ko = 2 * i + (rg >> 1);
    const int j0 = (rg & 1) * 4;               // 4 contiguous j
    u16x4 hi, lo;
#pragma unroll
    for (int rr = 0; rr < 4; ++rr) {
        unsigned short h = bf16_rne(v4[rr]);
        hi[rr] = h;
        lo[rr] = bf16_rne(v4[rr] - bf16_f32(h));
    }
    size_t off8 = (size_t)(mt * 32 + ko) * 16 + cc;    // u16x8 units
    Ahi4[off8 * 2 + (j0 >> 2)] = hi;
    Alo4[off8 * 2 + (j0 >> 2)] = lo;
    if (rg == 0) {
        float t = ps[0][m][16] + ps[1][m][16] + ps[2][m][16] + ps[3][m][16];
        rowsum_p[(size_t)i * M + gm] = t;
    }
}

__global__ __launch_bounds__(256) void rowsum_reduce(const float* __restrict__ rowsum_p,
                                                     float* __restrict__ rstot, int M) {
    int m = blockIdx.x * 256 + threadIdx.x;
    float s = 1.0f;
#pragma unroll
    for (int i = 0; i < NBLK; ++i) s += rowsum_p[(size_t)i * M + m];
    rstot[m] = s;
}

// out = T @ Ahat (split bf16 MFMA: hi*hi + hi*lo + lo*hi) + rstot[m]*bias[n]
// grid 512 blocks x 256 thr (4 waves, 2x2); block tile 64m x 256n; K=256.
__global__ __launch_bounds__(256) void apply_mfma(const bf16x8* __restrict__ Ahi,
                                                  const bf16x8* __restrict__ Alo,
                                                  const bf16x8* __restrict__ Bhi,
                                                  const bf16x8* __restrict__ Blo,
                                                  const float* __restrict__ rstot,
                                                  const float* __restrict__ bias,
                                                  float* __restrict__ out, int M) {
    const int mblocks = M >> 6;                 // 32
    const int nb  = blockIdx.x;
    const int q   = gridDim.x >> 3;             // per-XCD chunk (grid % 8 == 0)
    const int lg  = (nb & 7) * q + (nb >> 3);   // XCD-contiguous logical id
    const int mr  = lg % mblocks;
    const int nc  = lg / mblocks;               // same-nc blocks land on one XCD
    const int m0  = mr * 64, n0 = nc * 256;

    const int tid = threadIdx.x;
    const int l   = tid & 63;
    const int wid = __builtin_amdgcn_readfirstlane(tid >> 6);
    const int wm  = wid & 1, wn = wid >> 1;     // 2x2 waves: 32m x 128n each
    const int kq  = l >> 4, c = l & 15;

    f32x4 acc[2][8];
#pragma unroll
    for (int f = 0; f < 2; ++f)
#pragma unroll
        for (int nf = 0; nf < 8; ++nf) acc[f][nf] = f32x4{0.f, 0.f, 0.f, 0.f};

    const int mtb = (m0 >> 4) + wm * 2;
    const int ntb = nc * 16 + wn * 8;

#pragma unroll 2
    for (int s = 0; s < 8; ++s) {
        const int kb = 4 * s + kq;
        bf16x8 ah[2], al[2];
#pragma unroll
        for (int f = 0; f < 2; ++f) {
            size_t off = (size_t)((mtb + f) * 32 + kb) * 16 + c;
            ah[f] = Ahi[off];
            al[f] = Alo[off];
        }
#pragma unroll
        for (int nf = 0; nf < 8; ++nf) {
            size_t off = (size_t)((ntb + nf) * 32 + kb) * 16 + c;
            bf16x8 bh = Bhi[off];
            bf16x8 bl = Blo[off];
#pragma unroll
            for (int f = 0; f < 2; ++f) {
                acc[f][nf] = __builtin_amdgcn_mfma_f32_16x16x32_bf16(ah[f], bh, acc[f][nf], 0, 0, 0);
                acc[f][nf] = __builtin_amdgcn_mfma_f32_16x16x32_bf16(ah[f], bl, acc[f][nf], 0, 0, 0);
                acc[f][nf] = __builtin_amdgcn_mfma_f32_16x16x32_bf16(al[f], bh, acc[f][nf], 0, 0, 0);
            }
        }
    }

    // epilogue: out[m][n] = acc + rstot[m]*bias[n]   (C/D: row=kq*4+reg, col=c)
#pragma unroll
    for (int f = 0; f < 2; ++f) {
        const int rowb = m0 + wm * 32 + f * 16 + kq * 4;
        float rsv[4];
#pragma unroll
        for (int reg = 0; reg < 4; ++reg) rsv[reg] = rstot[rowb + reg];
#pragma unroll
        for (int nf = 0; nf < 8; ++nf) {
            const int n = n0 + wn * 128 + nf * 16 + c;
            const float bv = bias[n];
#pragma unroll
            for (int reg = 0; reg < 4; ++reg)
                out[(size_t)(rowb + reg) * OUT_DIM + n] = acc[f][nf][reg] + rsv[reg] * bv;
        }
    }
}

extern "C" void kernel_launch(void* const* d_in, const int* in_sizes, int n_in,
                              void* d_out, int out_size, void* d_ws, size_t ws_size,
                              hipStream_t stream) {
    const float* x    = (const float*)d_in[0];
    const float* S    = (const float*)d_in[1];
    const float* U    = (const float*)d_in[2];
    const float* Vt   = (const float*)d_in[3];
    const float* bias = (const float*)d_in[4];
    float* out = (float*)d_out;
    const int M = in_sizes[0] / IN_DIM;   // 2048

    char* ws = (char*)d_ws;
    u16x8* Bhi      = (u16x8*)ws;                                  // 2 MB
    u16x8* Blo      = (u16x8*)(ws + (2u << 20));                   // 2 MB
    u16x8* Ahi      = (u16x8*)(ws + (4u << 20));                   // 1 MB
    u16x8* Alo      = (u16x8*)(ws + (5u << 20));                   // 1 MB
    float* rowsum_p = (float*)(ws + (6u << 20));                   // 128 KB
    float* rstot    = (float*)(ws + (6u << 20) + NBLK * M * 4);    // 8 KB

    build_packB<<<512, 256, 0, stream>>>(S, U, Bhi, Blo);
    factor_x<<<dim3(M / 64, NBLK), 256, 0, stream>>>(x, Vt, (u16x4*)Ahi, (u16x4*)Alo,
                                                     rowsum_p, M);
    rowsum_reduce<<<M / 256, 256, 0, stream>>>(rowsum_p, rstot, M);
    apply_mfma<<<(M / 64) * (OUT_DIM / 256), 256, 0, stream>>>(
        reinterpret_cast<const bf16x8*>(Ahi), reinterpret_cast<const bf16x8*>(Alo),
        reinterpret_cast<const bf16x8*>(Bhi), reinterpret_cast<const bf16x8*>(Blo),
        rstot, bias, out, M);
}

// Round 4
// 113.997 us; speedup vs baseline: 1.5424x; 1.0171x over previous
//
#include <hip/hip_runtime.h>

#define IN_DIM  4096
#define OUT_DIM 4096
#define RANK    16
#define NBLK    16
#define KDIM    256   // NBLK*RANK

typedef __attribute__((ext_vector_type(8))) __bf16 bf16x8;
typedef __attribute__((ext_vector_type(4))) __bf16 bf16x4;
typedef __attribute__((ext_vector_type(4))) float  f32x4;

// ---------------------------------------------------------------------------
// Pack layouts (MFMA 16x16x32 fragment order), granularity = bf16x8 (16B):
//   PackA[mt(128)][ko(32)][c(16)] : 8 bf16 = T[mt*16+c][ko*8+j]   (A row=c)
//   PackB[nt(256)][ko(32)][c(16)] : 8 bf16 = Ahat[ko*8+j][nt*16+c](B col=c)
//   PackV[i(16)][ks(8)][qt(4)][c(16)] : 8 bf16 = Vt[i][ks*32+qt*8+j][c]
// k of apply GEMM: k = i*16 + r = ko*8 + j.
// All values split hi/lo bf16 (w = hi + lo to ~16-bit mantissa).
// ---------------------------------------------------------------------------

__device__ __forceinline__ void split_bf16(float v, __bf16& h, __bf16& l) {
    h = (__bf16)v;
    l = (__bf16)(v - (float)h);
}

// blocks 0..511: B-pack (Ahat = S*U).  blocks 512..543: Vt-pack.
__global__ __launch_bounds__(256) void build_packs(const float* __restrict__ S,
                                                   const float* __restrict__ U,
                                                   const float* __restrict__ Vt,
                                                   bf16x8* __restrict__ Bhi,
                                                   bf16x8* __restrict__ Blo,
                                                   bf16x8* __restrict__ Vhi,
                                                   bf16x8* __restrict__ Vlo) {
    const int blk = blockIdx.x;
    if (blk < 512) {
        int t  = blk * 256 + threadIdx.x;  // = (nt*32 + ko)*16 + c
        int c  = t & 15;
        int ko = (t >> 4) & 31;
        int nt = t >> 9;
        int o  = nt >> 4;
        int i  = ko >> 1;
        int q  = ((nt & 15) << 4) | c;
        int r0 = (ko & 1) << 3;
        const float* Sp = S + ((o * NBLK + i) * RANK + r0);
        const float* Up = U + (size_t)o * RANK * 256 + q;   // + r*256
        bf16x8 hi, lo;
#pragma unroll
        for (int j = 0; j < 8; ++j) {
            float w = Sp[j] * Up[(size_t)(r0 + j) * 256];
            __bf16 h, l;
            split_bf16(w, h, l);
            hi[j] = h; lo[j] = l;
        }
        Bhi[t] = hi;
        Blo[t] = lo;
    } else {
        int t  = (blk - 512) * 256 + threadIdx.x;  // = ((i*8+ks)*4+qt)*16 + c
        int c  = t & 15;
        int p0 = (t >> 4) << 3;                    // (ks*32 + qt*8) within block i
        int i  = t >> 9;
        int pbase = (p0 & 255);
        const float* vp = Vt + ((size_t)(i * 256 + pbase)) * RANK + c;
        bf16x8 hi, lo;
#pragma unroll
        for (int j = 0; j < 8; ++j) {
            float w = vp[(size_t)j * RANK];
            __bf16 h, l;
            split_bf16(w, h, l);
            hi[j] = h; lo[j] = l;
        }
        Vhi[t] = hi;
        Vlo[t] = lo;
    }
}

// Stage A via MFMA:  D[r][m] = sum_p Vt[i][p][r] * x[m][p]  (per (mt, i) job)
// A-operand = Vt-pack (row = r = lane&15), B-operand = x rows (col = m = lane&15,
// 8 contiguous floats per lane, converted to bf16 hi/lo in-register).
// Output C/D: col(lane&15) = m, row((lane>>4)*4+reg) = r  ->  bf16x4 store into A-pack.
__global__ __launch_bounds__(256) void factor_mfma(const float* __restrict__ x,
                                                   const bf16x8* __restrict__ Vhi,
                                                   const bf16x8* __restrict__ Vlo,
                                                   bf16x4* __restrict__ Ahi4,
                                                   bf16x4* __restrict__ Alo4,
                                                   float* __restrict__ rowsum_p,
                                                   int M) {
    const int tid = threadIdx.x;
    const int l   = tid & 63;
    const int w   = tid >> 6;
    const int job = blockIdx.x * 4 + w;     // (mt, i)
    const int i   = job & 15;
    const int mt  = job >> 4;
    const int row = l & 15;                 // m within tile (B col)
    const int qt  = l >> 4;                 // k-quarter

    const float* xp = x + (size_t)(mt * 16 + row) * IN_DIM + i * 256 + qt * 8;

    f32x4 acc = {0.f, 0.f, 0.f, 0.f};
    float rs = 0.f;
#pragma unroll
    for (int ks = 0; ks < 8; ++ks) {
        float4 a = *reinterpret_cast<const float4*>(xp + ks * 32);
        float4 b = *reinterpret_cast<const float4*>(xp + ks * 32 + 4);
        rs += (a.x + a.y) + (a.z + a.w) + (b.x + b.y) + (b.z + b.w);
        float vv[8] = {a.x, a.y, a.z, a.w, b.x, b.y, b.z, b.w};
        bf16x8 xh, xl;
#pragma unroll
        for (int jj = 0; jj < 8; ++jj) {
            __bf16 h, lo_;
            split_bf16(vv[jj], h, lo_);
            xh[jj] = h; xl[jj] = lo_;
        }
        size_t vidx = (size_t)((i * 8 + ks) * 4 + qt) * 16 + row;
        bf16x8 vh = Vhi[vidx];
        bf16x8 vl = Vlo[vidx];
        acc = __builtin_amdgcn_mfma_f32_16x16x32_bf16(vh, xh, acc, 0, 0, 0);
        acc = __builtin_amdgcn_mfma_f32_16x16x32_bf16(vh, xl, acc, 0, 0, 0);
        acc = __builtin_amdgcn_mfma_f32_16x16x32_bf16(vl, xh, acc, 0, 0, 0);
    }

    // rowsum over this i-block for row m: reduce across the 4 k-quarter groups
    rs += __shfl_xor(rs, 16, 64);
    rs += __shfl_xor(rs, 32, 64);
    if (l < 16)
        rowsum_p[(size_t)i * M + mt * 16 + l] = rs;

    // store T[m][i*16 + r], r = qt*4+reg  ->  A-pack (hi/lo), 8B per lane
    bf16x4 hi, lo;
#pragma unroll
    for (int reg = 0; reg < 4; ++reg) {
        __bf16 h, lo_;
        split_bf16(acc[reg], h, lo_);
        hi[reg] = h; lo[reg] = lo_;
    }
    size_t o4 = ((size_t)(mt * 32 + i * 2 + (l >> 5)) * 16 + row) * 2 + ((l >> 4) & 1);
    Ahi4[o4] = hi;
    Alo4[o4] = lo;
}

// out = T @ Ahat (split bf16: hi*hi + hi*lo + lo*hi) + (1+rowsum[m])*bias[n]
// grid 512 x 256 thr (2x2 waves); block tile 64m x 256n; K=256.
__global__ __launch_bounds__(256) void apply_mfma(const bf16x8* __restrict__ Ahi,
                                                  const bf16x8* __restrict__ Alo,
                                                  const bf16x8* __restrict__ Bhi,
                                                  const bf16x8* __restrict__ Blo,
                                                  const float* __restrict__ rowsum_p,
                                                  const float* __restrict__ bias,
                                                  float* __restrict__ out, int M) {
    const int mblocks = M >> 6;                 // 32
    const int nb  = blockIdx.x;
    const int q   = gridDim.x >> 3;             // per-XCD chunk (grid % 8 == 0)
    const int lg  = (nb & 7) * q + (nb >> 3);   // XCD-contiguous logical id
    const int mr  = lg % mblocks;
    const int nc  = lg / mblocks;               // same-nc blocks share one XCD's L2
    const int m0  = mr * 64, n0 = nc * 256;

    const int tid = threadIdx.x;
    const int l   = tid & 63;
    const int wid = __builtin_amdgcn_readfirstlane(tid >> 6);
    const int wm  = wid & 1, wn = wid >> 1;     // 2x2 waves: 32m x 128n each
    const int kq  = l >> 4, c = l & 15;

    // block-cooperative rstot for the 64 rows (kills the standalone reduce kernel)
    __shared__ float rstot_s[64];
    if (tid < 64) {
        float s = 1.0f;
#pragma unroll
        for (int i = 0; i < NBLK; ++i) s += rowsum_p[(size_t)i * M + m0 + tid];
        rstot_s[tid] = s;
    }
    __syncthreads();

    f32x4 acc[2][8];
#pragma unroll
    for (int f = 0; f < 2; ++f)
#pragma unroll
        for (int nf = 0; nf < 8; ++nf) acc[f][nf] = f32x4{0.f, 0.f, 0.f, 0.f};

    const int mtb = (m0 >> 4) + wm * 2;
    const int ntb = nc * 16 + wn * 8;

#pragma unroll 2
    for (int s = 0; s < 8; ++s) {
        const int kb = 4 * s + kq;
        bf16x8 ah[2], al[2];
#pragma unroll
        for (int f = 0; f < 2; ++f) {
            size_t off = (size_t)((mtb + f) * 32 + kb) * 16 + c;
            ah[f] = Ahi[off];
            al[f] = Alo[off];
        }
#pragma unroll
        for (int nf = 0; nf < 8; ++nf) {
            size_t off = (size_t)((ntb + nf) * 32 + kb) * 16 + c;
            bf16x8 bh = Bhi[off];
            bf16x8 bl = Blo[off];
#pragma unroll
            for (int f = 0; f < 2; ++f) {
                acc[f][nf] = __builtin_amdgcn_mfma_f32_16x16x32_bf16(ah[f], bh, acc[f][nf], 0, 0, 0);
                acc[f][nf] = __builtin_amdgcn_mfma_f32_16x16x32_bf16(ah[f], bl, acc[f][nf], 0, 0, 0);
                acc[f][nf] = __builtin_amdgcn_mfma_f32_16x16x32_bf16(al[f], bh, acc[f][nf], 0, 0, 0);
            }
        }
    }

    // epilogue: out[m][n] = acc + rstot[m]*bias[n]   (C/D: row=kq*4+reg, col=c)
#pragma unroll
    for (int f = 0; f < 2; ++f) {
        const int rloc = wm * 32 + f * 16 + kq * 4;
        const int rowb = m0 + rloc;
        float rsv[4];
#pragma unroll
        for (int reg = 0; reg < 4; ++reg) rsv[reg] = rstot_s[rloc + reg];
#pragma unroll
        for (int nf = 0; nf < 8; ++nf) {
            const int n = n0 + wn * 128 + nf * 16 + c;
            const float bv = bias[n];
#pragma unroll
            for (int reg = 0; reg < 4; ++reg)
                out[(size_t)(rowb + reg) * OUT_DIM + n] = acc[f][nf][reg] + rsv[reg] * bv;
        }
    }
}

extern "C" void kernel_launch(void* const* d_in, const int* in_sizes, int n_in,
                              void* d_out, int out_size, void* d_ws, size_t ws_size,
                              hipStream_t stream) {
    const float* x    = (const float*)d_in[0];
    const float* S    = (const float*)d_in[1];
    const float* U    = (const float*)d_in[2];
    const float* Vt   = (const float*)d_in[3];
    const float* bias = (const float*)d_in[4];
    float* out = (float*)d_out;
    const int M = in_sizes[0] / IN_DIM;   // 2048

    char* ws = (char*)d_ws;
    bf16x8* Bhi     = (bf16x8*)ws;                                    // 2 MB
    bf16x8* Blo     = (bf16x8*)(ws + (2u << 20));                     // 2 MB
    bf16x8* Ahi     = (bf16x8*)(ws + (4u << 20));                     // 1 MB
    bf16x8* Alo     = (bf16x8*)(ws + (5u << 20));                     // 1 MB
    bf16x8* Vhi     = (bf16x8*)(ws + (6u << 20));                     // 128 KB
    bf16x8* Vlo     = (bf16x8*)(ws + (6u << 20) + (128u << 10));      // 128 KB
    float* rowsum_p = (float*)(ws + (6u << 20) + (256u << 10));       // 128 KB

    build_packs<<<544, 256, 0, stream>>>(S, U, Vt, Bhi, Blo, Vhi, Vlo);
    factor_mfma<<<M / 4, 256, 0, stream>>>(x, Vhi, Vlo,
                                           (bf16x4*)Ahi, (bf16x4*)Alo, rowsum_p, M);
    apply_mfma<<<(M / 64) * (OUT_DIM / 256), 256, 0, stream>>>(
        Ahi, Alo, Bhi, Blo, rowsum_p, bias, out, M);
}